// Round 9
// baseline (135.415 us; speedup 1.0000x reference)
//
#include <hip/hip_runtime.h>
#include <math.h>

// LDR toep_corner via FFT chain, radix-16 registerized FFT (4096 = 16^3).
// out[j,b] = Re ifft( sum_{i,s} Gf_ijs . fft( D . fft( Hf_ijs . Xf_ib ) ) )
// Hf = fft(D.H), Xf = ifft(conj(D).x), Gf = fft(G), D_k = exp(i*pi*k/N).
//
// R9: NOTE the bench dur includes a fixed ~47us harness fill (0xAA poison of
// the whole 256MB d_ws) — our kernels are only ~55-60us of the total.
// Changes vs R8: mid NS=2 (grid 1024 = 4 blocks/CU, acc[8] half-spectrum,
// Ph 32->16MB), pruned stage C on mid's 2nd FFT (only k<=8 outputs used),
// fin reads 8 planes with float4, dual-chain twiddle powers.
// Kept: NS>=2 register watch (cap 256 via launch_bounds(256,2); R4/R5 proved
// (256,4) -> VGPR=64 -> catastrophic spill), 32KB single-buffer FFT,
// XOR bank swizzle, half-spectrum Ph with DC/Nyquist packed in elem 0.

#define NFFT  4096
#define NT    256
#define CIN   4
#define COUT  4
#define RANK  4
#define BATCH 32
#define PI_F  3.14159265358979323846f

__device__ __forceinline__ float2 cmul(float2 a, float2 b) {
    return make_float2(a.x*b.x - a.y*b.y, a.x*b.y + a.y*b.x);
}
__device__ __forceinline__ float2 cadd(float2 a, float2 b){ return make_float2(a.x+b.x, a.y+b.y); }
__device__ __forceinline__ float2 csub(float2 a, float2 b){ return make_float2(a.x-b.x, a.y-b.y); }

// LDS bank swizzle (R2-proven: SQ_LDS_BANK_CONFLICT ~ 0).
__device__ __forceinline__ int SW(int e){ return e ^ ((e >> 4) & 15); }

// 16-point DFT in registers, natural order in/out (R2-proven numerics).
template<int SIGN>
__device__ __forceinline__ void dft16(float2 v[16]) {
    const float sgn = (float)SIGN;
    const float C8 = 0.923879532511287f, S8 = 0.382683432365090f, H2 = 0.707106781186548f;
    const float2 w1 = make_float2( C8,  sgn*S8);
    const float2 w2 = make_float2( H2,  sgn*H2);
    const float2 w3 = make_float2( S8,  sgn*C8);
    const float2 w4 = make_float2(0.f,  sgn);
    const float2 w6 = make_float2(-H2,  sgn*H2);
    const float2 w9 = make_float2(-C8, -sgn*S8);
    float2 t[16];
    #pragma unroll
    for (int p = 0; p < 4; ++p) {
        float2 a0 = v[p], a1 = v[p+4], a2 = v[p+8], a3 = v[p+12];
        float2 b0 = cadd(a0,a2), b1 = csub(a0,a2), b2 = cadd(a1,a3), b3 = csub(a1,a3);
        float2 ib3 = make_float2(-sgn*b3.y, sgn*b3.x);   // SIGN*i*b3
        float2 X0 = cadd(b0,b2), X2c = csub(b0,b2);
        float2 X1 = cadd(b1,ib3), X3 = csub(b1,ib3);
        if (p == 1) { X1 = cmul(X1,w1); X2c = cmul(X2c,w2); X3 = cmul(X3,w3); }
        else if (p == 2) { X1 = cmul(X1,w2); X2c = cmul(X2c,w4); X3 = cmul(X3,w6); }
        else if (p == 3) { X1 = cmul(X1,w3); X2c = cmul(X2c,w6); X3 = cmul(X3,w9); }
        t[4*p+0]=X0; t[4*p+1]=X1; t[4*p+2]=X2c; t[4*p+3]=X3;
    }
    #pragma unroll
    for (int q = 0; q < 4; ++q) {
        float2 a0 = t[q], a1 = t[q+4], a2 = t[q+8], a3 = t[q+12];
        float2 b0 = cadd(a0,a2), b1 = csub(a0,a2), b2 = cadd(a1,a3), b3 = csub(a1,a3);
        float2 ib3 = make_float2(-sgn*b3.y, sgn*b3.x);
        v[q+0]  = cadd(b0,b2);
        v[q+8]  = csub(b0,b2);
        v[q+4]  = cadd(b1,ib3);
        v[q+12] = csub(b1,ib3);
    }
}

// Same, but second pass computes only outputs 0..7 plus v[8] (Nyquist lane).
template<int SIGN>
__device__ __forceinline__ void dft16_low(float2 v[16]) {
    const float sgn = (float)SIGN;
    const float C8 = 0.923879532511287f, S8 = 0.382683432365090f, H2 = 0.707106781186548f;
    const float2 w1 = make_float2( C8,  sgn*S8);
    const float2 w2 = make_float2( H2,  sgn*H2);
    const float2 w3 = make_float2( S8,  sgn*C8);
    const float2 w4 = make_float2(0.f,  sgn);
    const float2 w6 = make_float2(-H2,  sgn*H2);
    const float2 w9 = make_float2(-C8, -sgn*S8);
    float2 t[16];
    #pragma unroll
    for (int p = 0; p < 4; ++p) {
        float2 a0 = v[p], a1 = v[p+4], a2 = v[p+8], a3 = v[p+12];
        float2 b0 = cadd(a0,a2), b1 = csub(a0,a2), b2 = cadd(a1,a3), b3 = csub(a1,a3);
        float2 ib3 = make_float2(-sgn*b3.y, sgn*b3.x);
        float2 X0 = cadd(b0,b2), X2c = csub(b0,b2);
        float2 X1 = cadd(b1,ib3), X3 = csub(b1,ib3);
        if (p == 1) { X1 = cmul(X1,w1); X2c = cmul(X2c,w2); X3 = cmul(X3,w3); }
        else if (p == 2) { X1 = cmul(X1,w2); X2c = cmul(X2c,w4); X3 = cmul(X3,w6); }
        else if (p == 3) { X1 = cmul(X1,w3); X2c = cmul(X2c,w6); X3 = cmul(X3,w9); }
        t[4*p+0]=X0; t[4*p+1]=X1; t[4*p+2]=X2c; t[4*p+3]=X3;
    }
    #pragma unroll
    for (int q = 0; q < 4; ++q) {
        float2 a0 = t[q], a1 = t[q+4], a2 = t[q+8], a3 = t[q+12];
        float2 b0 = cadd(a0,a2), b1 = csub(a0,a2), b2 = cadd(a1,a3), b3 = csub(a1,a3);
        float2 ib3 = make_float2(-sgn*b3.y, sgn*b3.x);
        v[q+0]  = cadd(b0,b2);
        v[q+4]  = cadd(b1,ib3);
        if (q == 0) v[8] = csub(b0,b2);   // Nyquist column only
    }
}

// v[k] *= e^{i*k*ang}; two independent power chains (depth ~8 not 15).
__device__ __forceinline__ void twiddle16(float2 v[16], float ang) {
    float sn, cs; __sincosf(ang, &sn, &cs);
    float2 w  = make_float2(cs, sn);
    float2 w2 = cmul(w, w);
    float2 to = w;   // odd powers: 1,3,5,...
    float2 te = w2;  // even powers: 2,4,6,...
    v[1] = cmul(v[1], to);
    v[2] = cmul(v[2], te);
    #pragma unroll
    for (int k = 3; k < 16; k += 2) {
        to = cmul(to, w2); v[k] = cmul(v[k], to);
        if (k + 1 < 16) { te = cmul(te, w2); v[k+1] = cmul(v[k+1], te); }
    }
}

// Stockham radix-16, 3 stages, single 32KB buffer (R2-proven).
// Input: v[r] = x[tid + 256r]. Output: v[k] = X[tid + 256k].
template<int SIGN>
__device__ void fft4096_r16(float2 v[16], float2* lds, int tid) {
    dft16<SIGN>(v);
    twiddle16(v, (float)SIGN * 2.0f * PI_F * (float)tid / 4096.0f);
    #pragma unroll
    for (int k = 0; k < 16; ++k) lds[SW(16*tid + k)] = v[k];
    __syncthreads();
    #pragma unroll
    for (int r = 0; r < 16; ++r) v[r] = lds[SW(tid + 256*r)];
    dft16<SIGN>(v);
    twiddle16(v, (float)SIGN * 2.0f * PI_F * (float)(tid >> 4) / 256.0f);
    __syncthreads();                       // in-place: all reads before any write
    {
        const int q = tid & 15, p = tid >> 4;
        #pragma unroll
        for (int k = 0; k < 16; ++k) lds[SW(q + 256*p + 16*k)] = v[k];
    }
    __syncthreads();
    #pragma unroll
    for (int r = 0; r < 16; ++r) v[r] = lds[SW(tid + 256*r)];
    dft16<SIGN>(v);
    __syncthreads();                       // lds reusable by caller
}

// Forward FFT with pruned stage C (outputs k=0..8 only). TAIL_SYNC controls
// the trailing barrier (needed iff lds is reused afterwards).
template<bool TAIL_SYNC>
__device__ void fft4096_fwd_low(float2 v[16], float2* lds, int tid) {
    dft16<-1>(v);
    twiddle16(v, -2.0f * PI_F * (float)tid / 4096.0f);
    #pragma unroll
    for (int k = 0; k < 16; ++k) lds[SW(16*tid + k)] = v[k];
    __syncthreads();
    #pragma unroll
    for (int r = 0; r < 16; ++r) v[r] = lds[SW(tid + 256*r)];
    dft16<-1>(v);
    twiddle16(v, -2.0f * PI_F * (float)(tid >> 4) / 256.0f);
    __syncthreads();
    {
        const int q = tid & 15, p = tid >> 4;
        #pragma unroll
        for (int k = 0; k < 16; ++k) lds[SW(q + 256*p + 16*k)] = v[k];
    }
    __syncthreads();
    #pragma unroll
    for (int r = 0; r < 16; ++r) v[r] = lds[SW(tid + 256*r)];
    dft16_low<-1>(v);
    if (TAIL_SYNC) __syncthreads();
}

// ---- Kernel A: precompute Hf (64 rows), Gf (64 rows), Xf (128 rows) ----
__global__ __launch_bounds__(NT, 2) void ldr_pre_k(
    const float* __restrict__ x, const float* __restrict__ G, const float* __restrict__ H,
    float2* __restrict__ Hf, float2* __restrict__ Gf, float2* __restrict__ Xf)
{
    __shared__ float2 lds[NFFT];
    const int tid = threadIdx.x;
    const int bid = blockIdx.x;
    float2 v[16];
    if (bid < 64) {
        const float* h = H + (size_t)bid * NFFT;
        float sn, cs; __sincosf(PI_F * (float)tid / (float)NFFT, &sn, &cs);
        float2 d = make_float2(cs, sn);
        const float2 dstep = make_float2(0.980785280403230449f, 0.195090322016128268f); // e^{i*pi/16}
        #pragma unroll
        for (int k = 0; k < 16; ++k) {
            float hv = h[tid + 256*k];
            v[k] = make_float2(d.x*hv, d.y*hv);
            d = cmul(d, dstep);
        }
        fft4096_r16<-1>(v, lds, tid);
        float2* o = Hf + (size_t)bid * NFFT;
        #pragma unroll
        for (int k = 0; k < 16; ++k) o[tid + 256*k] = v[k];
    } else if (bid < 128) {
        const int row = bid - 64;
        const float* g = G + (size_t)row * NFFT;
        #pragma unroll
        for (int k = 0; k < 16; ++k) v[k] = make_float2(g[tid + 256*k], 0.0f);
        fft4096_r16<-1>(v, lds, tid);
        float2* o = Gf + (size_t)row * NFFT;
        #pragma unroll
        for (int k = 0; k < 16; ++k) o[tid + 256*k] = v[k];
    } else {
        const int row = bid - 128;
        const float* xp = x + (size_t)row * NFFT;
        float sn, cs; __sincosf(PI_F * (float)tid / (float)NFFT, &sn, &cs);
        float2 d = make_float2(cs, -sn);                                                 // conj(D)
        const float2 dstep = make_float2(0.980785280403230449f, -0.195090322016128268f);
        #pragma unroll
        for (int k = 0; k < 16; ++k) {
            float xv = xp[tid + 256*k];
            v[k] = make_float2(d.x*xv, d.y*xv);
            d = cmul(d, dstep);
        }
        fft4096_r16<1>(v, lds, tid);
        const float invn = 1.0f / (float)NFFT;
        float2* o = Xf + (size_t)row * NFFT;
        #pragma unroll
        for (int k = 0; k < 16; ++k) o[tid + 256*k] = make_float2(v[k].x*invn, v[k].y*invn);
    }
}

// ---- Kernel B: middle. grid 1024 = is2(32) x b(32), is2 = ij*2 + sg.
// Each wg: 2 rank-units (s = 2sg, 2sg+1), acc[8] = lower-half spectrum of
// sum_s Gf . fft(D . fft(Hf . Xf)); Nyquist accumulated separately.
// Store plane u = i*2 + sg (8 planes), row ((u*COUT+j)*BATCH+b), 2048 c64.
__global__ __launch_bounds__(NT, 2) void ldr_mid_k(
    const float2* __restrict__ Hf, const float2* __restrict__ Xf,
    const float2* __restrict__ Gf, float2* __restrict__ Ph)
{
    __shared__ float2 lds[NFFT];
    const int tid = threadIdx.x;
    const int bid = blockIdx.x;
    const int b   = bid & (BATCH - 1);
    const int is2 = bid >> 5;           // ij*2 + sg, [0,32)
    const int sg  = is2 & 1;
    const int ij  = is2 >> 1;
    const int i   = ij >> 2;            // COUT = 4
    const int j   = ij & 3;
    const float2* xrow = Xf + (size_t)(i*BATCH + b) * NFFT;

    float2 acc[8];
    float  accNyq = 0.0f;
    #pragma unroll
    for (int k = 0; k < 8; ++k) acc[k] = make_float2(0.0f, 0.0f);

    #pragma unroll
    for (int ss = 0; ss < 2; ++ss) {
        const int row = ij*RANK + sg*2 + ss;
        const float2* hrow = Hf + (size_t)row * NFFT;
        const float2* grow = Gf + (size_t)row * NFFT;
        float2 v[16];
        #pragma unroll
        for (int k = 0; k < 16; ++k) {
            const int e = tid + 256*k;
            v[k] = cmul(hrow[e], xrow[e]);
        }
        fft4096_r16<-1>(v, lds, tid);
        // multiply by D: elem e = tid + 256k, D_e = e^{i*pi*e/N}
        {
            float sn, cs; __sincosf(PI_F * (float)tid / (float)NFFT, &sn, &cs);
            float2 d = make_float2(cs, sn);
            const float2 dstep = make_float2(0.980785280403230449f, 0.195090322016128268f);
            #pragma unroll
            for (int k = 0; k < 16; ++k) { v[k] = cmul(v[k], d); d = cmul(d, dstep); }
        }
        if (ss == 0) fft4096_fwd_low<true >(v, lds, tid);
        else         fft4096_fwd_low<false>(v, lds, tid);
        #pragma unroll
        for (int k = 0; k < 8; ++k) {
            const int e = tid + 256*k;
            acc[k] = cadd(acc[k], cmul(grow[e], v[k]));
        }
        // Nyquist (element 2048 lives at tid==0, k==8); uniform compute, only
        // tid 0's value is meaningful/stored.
        accNyq += cmul(grow[2048], v[8]).x;
    }

    const int u = i*2 + sg;             // plane in [0,8)
    float2* prow = Ph + (size_t)((u*COUT + j)*BATCH + b) * (NFFT/2);
    float2 y0 = acc[0];
    if (tid == 0) y0 = make_float2(acc[0].x, accNyq);   // pack DC.x / Nyq
    prow[tid] = y0;
    #pragma unroll
    for (int k = 1; k < 8; ++k) prow[tid + 256*k] = acc[k];
}

// ---- Kernel C: final. grid 128 = (j,b). Sum 8 half-rows (float4 loads),
// mirror upper half by conjugate symmetry, one inverse FFT, write Re/N.
__global__ __launch_bounds__(NT, 2) void ldr_fin_k(
    const float2* __restrict__ Ph, float* __restrict__ out)
{
    __shared__ float2 lds[NFFT];
    __shared__ float2 sh[NFFT/2];      // summed half-spectrum (packed elem 0)
    const int tid = threadIdx.x;
    const int bid = blockIdx.x;        // j*BATCH + b
    const int b = bid & (BATCH - 1);
    const int j = bid >> 5;

    float4 a4[4];
    #pragma unroll
    for (int k = 0; k < 4; ++k) a4[k] = make_float4(0.f, 0.f, 0.f, 0.f);
    #pragma unroll
    for (int u = 0; u < 8; ++u) {
        const float4* row4 = (const float4*)(Ph + (size_t)((u*COUT + j)*BATCH + b) * (NFFT/2));
        #pragma unroll
        for (int k = 0; k < 4; ++k) {
            float4 t = row4[tid + 256*k];
            a4[k].x += t.x; a4[k].y += t.y; a4[k].z += t.z; a4[k].w += t.w;
        }
    }
    float4* sh4 = (float4*)sh;
    #pragma unroll
    for (int k = 0; k < 4; ++k) sh4[tid + 256*k] = a4[k];
    __syncthreads();

    const float dc  = sh[0].x;         // broadcast reads
    const float nyq = sh[0].y;
    float2 v[16];
    #pragma unroll
    for (int k = 0; k < 8; ++k) v[k] = sh[tid + 256*k];
    if (tid == 0) v[0] = make_float2(dc, 0.0f);
    #pragma unroll
    for (int k = 8; k < 16; ++k) {
        const int m = 4096 - (tid + 256*k);          // mirror index in [1,2048]
        if (m == 2048) {                              // only tid==0, k==8
            v[k] = make_float2(nyq, 0.0f);
        } else {
            float2 c = sh[m];
            v[k] = make_float2(c.x, -c.y);            // conj
        }
    }
    // no barrier needed: fft writes lds[], sh[] untouched
    fft4096_r16<1>(v, lds, tid);
    const float invn = 1.0f / (float)NFFT;
    float* orow = out + (size_t)bid * NFFT;
    #pragma unroll
    for (int k = 0; k < 16; ++k) orow[tid + 256*k] = v[k].x * invn;
}

extern "C" void kernel_launch(void* const* d_in, const int* in_sizes, int n_in,
                              void* d_out, int out_size, void* d_ws, size_t ws_size,
                              hipStream_t stream) {
    const float* x = (const float*)d_in[0];   // (CIN, B, N)
    const float* G = (const float*)d_in[1];   // (CIN, COUT, R, N)
    const float* H = (const float*)d_in[2];   // (CIN, COUT, R, N)
    float* out = (float*)d_out;               // (COUT, B, N)

    float2* Hf = (float2*)d_ws;                     // 64 rows  (2 MB)
    float2* Gf = Hf + (size_t)64 * NFFT;            // 64 rows  (2 MB)
    float2* Xf = Gf + (size_t)64 * NFFT;            // 128 rows (4 MB)
    float2* Ph = Xf + (size_t)128 * NFFT;           // 1024 half-rows x 2048 c64 (16 MB)

    ldr_pre_k<<<256, NT, 0, stream>>>(x, G, H, Hf, Gf, Xf);
    ldr_mid_k<<<CIN * COUT * RANK * BATCH / 2, NT, 0, stream>>>(Hf, Xf, Gf, Ph);
    ldr_fin_k<<<COUT * BATCH, NT, 0, stream>>>(Ph, out);
}

// Round 10
// 104.568 us; speedup vs baseline: 1.2950x; 1.2950x over previous
//
#include <hip/hip_runtime.h>
#include <hip/hip_fp16.h>
#include <math.h>

// LDR toep_corner via FFT chain, radix-16 registerized FFT (4096 = 16^3).
// out[j,b] = Re ifft( sum_{i,s} Gf_ijs . fft( D . fft( Hf_ijs . Xf_ib ) ) )
// Hf = fft(D.H), Xf = ifft(conj(D).x), Gf = fft(G), D_k = exp(i*pi*k/N).
//
// R10: R8's spill-free NS=1 mid (R9's acc-across-FFT regs forced VGPR=128 +
// 85MB scratch spill — any reg array live across fft4096 spills) + fp16
// half-spectrum partials (Ph 32->16MB; |Y|~25, fp16 rel 1e-3 -> out err
// ~1e-3 << 0.164 threshold). Pruned stage C + dual-chain twiddles kept.
// Fixed cost reminder: ~47us of dur is the harness's 256MB d_ws 0xAA fill.

#define NFFT  4096
#define NT    256
#define CIN   4
#define COUT  4
#define RANK  4
#define BATCH 32
#define PI_F  3.14159265358979323846f

__device__ __forceinline__ float2 cmul(float2 a, float2 b) {
    return make_float2(a.x*b.x - a.y*b.y, a.x*b.y + a.y*b.x);
}
__device__ __forceinline__ float2 cadd(float2 a, float2 b){ return make_float2(a.x+b.x, a.y+b.y); }
__device__ __forceinline__ float2 csub(float2 a, float2 b){ return make_float2(a.x-b.x, a.y-b.y); }

// LDS bank swizzle (R2-proven: SQ_LDS_BANK_CONFLICT ~ 0).
__device__ __forceinline__ int SW(int e){ return e ^ ((e >> 4) & 15); }

// 16-point DFT in registers, natural order in/out (R2-proven numerics).
template<int SIGN>
__device__ __forceinline__ void dft16(float2 v[16]) {
    const float sgn = (float)SIGN;
    const float C8 = 0.923879532511287f, S8 = 0.382683432365090f, H2 = 0.707106781186548f;
    const float2 w1 = make_float2( C8,  sgn*S8);
    const float2 w2 = make_float2( H2,  sgn*H2);
    const float2 w3 = make_float2( S8,  sgn*C8);
    const float2 w4 = make_float2(0.f,  sgn);
    const float2 w6 = make_float2(-H2,  sgn*H2);
    const float2 w9 = make_float2(-C8, -sgn*S8);
    float2 t[16];
    #pragma unroll
    for (int p = 0; p < 4; ++p) {
        float2 a0 = v[p], a1 = v[p+4], a2 = v[p+8], a3 = v[p+12];
        float2 b0 = cadd(a0,a2), b1 = csub(a0,a2), b2 = cadd(a1,a3), b3 = csub(a1,a3);
        float2 ib3 = make_float2(-sgn*b3.y, sgn*b3.x);   // SIGN*i*b3
        float2 X0 = cadd(b0,b2), X2c = csub(b0,b2);
        float2 X1 = cadd(b1,ib3), X3 = csub(b1,ib3);
        if (p == 1) { X1 = cmul(X1,w1); X2c = cmul(X2c,w2); X3 = cmul(X3,w3); }
        else if (p == 2) { X1 = cmul(X1,w2); X2c = cmul(X2c,w4); X3 = cmul(X3,w6); }
        else if (p == 3) { X1 = cmul(X1,w3); X2c = cmul(X2c,w6); X3 = cmul(X3,w9); }
        t[4*p+0]=X0; t[4*p+1]=X1; t[4*p+2]=X2c; t[4*p+3]=X3;
    }
    #pragma unroll
    for (int q = 0; q < 4; ++q) {
        float2 a0 = t[q], a1 = t[q+4], a2 = t[q+8], a3 = t[q+12];
        float2 b0 = cadd(a0,a2), b1 = csub(a0,a2), b2 = cadd(a1,a3), b3 = csub(a1,a3);
        float2 ib3 = make_float2(-sgn*b3.y, sgn*b3.x);
        v[q+0]  = cadd(b0,b2);
        v[q+8]  = csub(b0,b2);
        v[q+4]  = cadd(b1,ib3);
        v[q+12] = csub(b1,ib3);
    }
}

// Second pass computing only outputs 0..7 plus v[8] (Nyquist lane).
template<int SIGN>
__device__ __forceinline__ void dft16_low(float2 v[16]) {
    const float sgn = (float)SIGN;
    const float C8 = 0.923879532511287f, S8 = 0.382683432365090f, H2 = 0.707106781186548f;
    const float2 w1 = make_float2( C8,  sgn*S8);
    const float2 w2 = make_float2( H2,  sgn*H2);
    const float2 w3 = make_float2( S8,  sgn*C8);
    const float2 w4 = make_float2(0.f,  sgn);
    const float2 w6 = make_float2(-H2,  sgn*H2);
    const float2 w9 = make_float2(-C8, -sgn*S8);
    float2 t[16];
    #pragma unroll
    for (int p = 0; p < 4; ++p) {
        float2 a0 = v[p], a1 = v[p+4], a2 = v[p+8], a3 = v[p+12];
        float2 b0 = cadd(a0,a2), b1 = csub(a0,a2), b2 = cadd(a1,a3), b3 = csub(a1,a3);
        float2 ib3 = make_float2(-sgn*b3.y, sgn*b3.x);
        float2 X0 = cadd(b0,b2), X2c = csub(b0,b2);
        float2 X1 = cadd(b1,ib3), X3 = csub(b1,ib3);
        if (p == 1) { X1 = cmul(X1,w1); X2c = cmul(X2c,w2); X3 = cmul(X3,w3); }
        else if (p == 2) { X1 = cmul(X1,w2); X2c = cmul(X2c,w4); X3 = cmul(X3,w6); }
        else if (p == 3) { X1 = cmul(X1,w3); X2c = cmul(X2c,w6); X3 = cmul(X3,w9); }
        t[4*p+0]=X0; t[4*p+1]=X1; t[4*p+2]=X2c; t[4*p+3]=X3;
    }
    #pragma unroll
    for (int q = 0; q < 4; ++q) {
        float2 a0 = t[q], a1 = t[q+4], a2 = t[q+8], a3 = t[q+12];
        float2 b0 = cadd(a0,a2), b1 = csub(a0,a2), b2 = cadd(a1,a3), b3 = csub(a1,a3);
        float2 ib3 = make_float2(-sgn*b3.y, sgn*b3.x);
        v[q+0]  = cadd(b0,b2);
        v[q+4]  = cadd(b1,ib3);
        if (q == 0) v[8] = csub(b0,b2);   // Nyquist column only
    }
}

// v[k] *= e^{i*k*ang}; two independent power chains (depth ~8 not 15).
__device__ __forceinline__ void twiddle16(float2 v[16], float ang) {
    float sn, cs; __sincosf(ang, &sn, &cs);
    float2 w  = make_float2(cs, sn);
    float2 w2 = cmul(w, w);
    float2 to = w;   // odd powers
    float2 te = w2;  // even powers
    v[1] = cmul(v[1], to);
    v[2] = cmul(v[2], te);
    #pragma unroll
    for (int k = 3; k < 16; k += 2) {
        to = cmul(to, w2); v[k] = cmul(v[k], to);
        if (k + 1 < 16) { te = cmul(te, w2); v[k+1] = cmul(v[k+1], te); }
    }
}

// Stockham radix-16, 3 stages, single 32KB buffer (R2-proven).
// Input: v[r] = x[tid + 256r]. Output: v[k] = X[tid + 256k].
template<int SIGN>
__device__ void fft4096_r16(float2 v[16], float2* lds, int tid) {
    dft16<SIGN>(v);
    twiddle16(v, (float)SIGN * 2.0f * PI_F * (float)tid / 4096.0f);
    #pragma unroll
    for (int k = 0; k < 16; ++k) lds[SW(16*tid + k)] = v[k];
    __syncthreads();
    #pragma unroll
    for (int r = 0; r < 16; ++r) v[r] = lds[SW(tid + 256*r)];
    dft16<SIGN>(v);
    twiddle16(v, (float)SIGN * 2.0f * PI_F * (float)(tid >> 4) / 256.0f);
    __syncthreads();                       // in-place: all reads before any write
    {
        const int q = tid & 15, p = tid >> 4;
        #pragma unroll
        for (int k = 0; k < 16; ++k) lds[SW(q + 256*p + 16*k)] = v[k];
    }
    __syncthreads();
    #pragma unroll
    for (int r = 0; r < 16; ++r) v[r] = lds[SW(tid + 256*r)];
    dft16<SIGN>(v);
    __syncthreads();                       // lds reusable by caller
}

// Forward FFT with pruned stage C (outputs k=0..8 only), no tail barrier
// (lds not reused after in mid).
__device__ void fft4096_fwd_low(float2 v[16], float2* lds, int tid) {
    dft16<-1>(v);
    twiddle16(v, -2.0f * PI_F * (float)tid / 4096.0f);
    #pragma unroll
    for (int k = 0; k < 16; ++k) lds[SW(16*tid + k)] = v[k];
    __syncthreads();
    #pragma unroll
    for (int r = 0; r < 16; ++r) v[r] = lds[SW(tid + 256*r)];
    dft16<-1>(v);
    twiddle16(v, -2.0f * PI_F * (float)(tid >> 4) / 256.0f);
    __syncthreads();
    {
        const int q = tid & 15, p = tid >> 4;
        #pragma unroll
        for (int k = 0; k < 16; ++k) lds[SW(q + 256*p + 16*k)] = v[k];
    }
    __syncthreads();
    #pragma unroll
    for (int r = 0; r < 16; ++r) v[r] = lds[SW(tid + 256*r)];
    dft16_low<-1>(v);
}

// ---- Kernel A: precompute Hf (64 rows), Gf (64 rows), Xf (128 rows) ----
__global__ __launch_bounds__(NT, 2) void ldr_pre_k(
    const float* __restrict__ x, const float* __restrict__ G, const float* __restrict__ H,
    float2* __restrict__ Hf, float2* __restrict__ Gf, float2* __restrict__ Xf)
{
    __shared__ float2 lds[NFFT];
    const int tid = threadIdx.x;
    const int bid = blockIdx.x;
    float2 v[16];
    if (bid < 64) {
        const float* h = H + (size_t)bid * NFFT;
        float sn, cs; __sincosf(PI_F * (float)tid / (float)NFFT, &sn, &cs);
        float2 d = make_float2(cs, sn);
        const float2 dstep = make_float2(0.980785280403230449f, 0.195090322016128268f); // e^{i*pi/16}
        #pragma unroll
        for (int k = 0; k < 16; ++k) {
            float hv = h[tid + 256*k];
            v[k] = make_float2(d.x*hv, d.y*hv);
            d = cmul(d, dstep);
        }
        fft4096_r16<-1>(v, lds, tid);
        float2* o = Hf + (size_t)bid * NFFT;
        #pragma unroll
        for (int k = 0; k < 16; ++k) o[tid + 256*k] = v[k];
    } else if (bid < 128) {
        const int row = bid - 64;
        const float* g = G + (size_t)row * NFFT;
        #pragma unroll
        for (int k = 0; k < 16; ++k) v[k] = make_float2(g[tid + 256*k], 0.0f);
        fft4096_r16<-1>(v, lds, tid);
        float2* o = Gf + (size_t)row * NFFT;
        #pragma unroll
        for (int k = 0; k < 16; ++k) o[tid + 256*k] = v[k];
    } else {
        const int row = bid - 128;
        const float* xp = x + (size_t)row * NFFT;
        float sn, cs; __sincosf(PI_F * (float)tid / (float)NFFT, &sn, &cs);
        float2 d = make_float2(cs, -sn);                                                 // conj(D)
        const float2 dstep = make_float2(0.980785280403230449f, -0.195090322016128268f);
        #pragma unroll
        for (int k = 0; k < 16; ++k) {
            float xv = xp[tid + 256*k];
            v[k] = make_float2(d.x*xv, d.y*xv);
            d = cmul(d, dstep);
        }
        fft4096_r16<1>(v, lds, tid);
        const float invn = 1.0f / (float)NFFT;
        float2* o = Xf + (size_t)row * NFFT;
        #pragma unroll
        for (int k = 0; k < 16; ++k) o[tid + 256*k] = make_float2(v[k].x*invn, v[k].y*invn);
    }
}

// ---- Kernel B: middle. grid 2048 = (ij*RANK+s)(64) x b(32); one rank-unit
// per wg, NO registers live across FFT calls (spill-free, R7/R8-proven).
// Y = Gf . fft(D . fft(Hf . Xf)) is conjugate-symmetric; store lower half
// k=0..2047 as fp16 (__half2 re/im), DC.x/Nyquist packed into element 0.
// Plane u = i*RANK + s (16 planes), row ((u*COUT+j)*BATCH+b), 2048 half2.
__global__ __launch_bounds__(NT, 2) void ldr_mid_k(
    const float2* __restrict__ Hf, const float2* __restrict__ Xf,
    const float2* __restrict__ Gf, __half2* __restrict__ Ph)
{
    __shared__ float2 lds[NFFT];
    const int tid = threadIdx.x;
    const int bid = blockIdx.x;
    const int b   = bid & (BATCH - 1);
    const int is_ = bid >> 5;           // ij*RANK + s  (row into Hf/Gf)
    const int s   = is_ & 3;
    const int ij  = is_ >> 2;
    const int i   = ij >> 2;            // COUT = 4
    const int j   = ij & 3;
    const float2* xrow = Xf + (size_t)(i*BATCH + b) * NFFT;
    const float2* hrow = Hf + (size_t)is_ * NFFT;
    const float2* grow = Gf + (size_t)is_ * NFFT;

    float2 v[16];
    #pragma unroll
    for (int k = 0; k < 16; ++k) {
        const int e = tid + 256*k;
        v[k] = cmul(hrow[e], xrow[e]);
    }
    fft4096_r16<-1>(v, lds, tid);
    // multiply by D: elem e = tid + 256k, D_e = e^{i*pi*e/N}
    {
        float sn, cs; __sincosf(PI_F * (float)tid / (float)NFFT, &sn, &cs);
        float2 d = make_float2(cs, sn);
        const float2 dstep = make_float2(0.980785280403230449f, 0.195090322016128268f);
        #pragma unroll
        for (int k = 0; k < 16; ++k) { v[k] = cmul(v[k], d); d = cmul(d, dstep); }
    }
    fft4096_fwd_low(v, lds, tid);
    // Y[e] = Gf[e] * v[e], store lower half as fp16.
    const int u = i * RANK + s;         // plane in [0,16)
    __half2* prow = Ph + (size_t)((u*COUT + j)*BATCH + b) * (NFFT/2);
    float2 y0 = cmul(grow[tid], v[0]);
    if (tid == 0) {
        const float2 ynyq = cmul(grow[2048], v[8]);   // e = 2048 (tid=0,k=8)
        y0 = make_float2(y0.x, ynyq.x);               // pack DC.x / Nyq.x
    }
    prow[tid] = __floats2half2_rn(y0.x, y0.y);
    #pragma unroll
    for (int k = 1; k < 8; ++k) {
        const int e = tid + 256*k;
        const float2 y = cmul(grow[e], v[k]);
        prow[e] = __floats2half2_rn(y.x, y.y);
    }
}

// ---- Kernel C: final. grid 128 = (j,b). Sum 16 fp16 half-rows via int4
// loads (4 complex per load), mirror upper half by conjugate symmetry,
// one inverse FFT, write Re/N.
__global__ __launch_bounds__(NT, 2) void ldr_fin_k(
    const __half2* __restrict__ Ph, float* __restrict__ out)
{
    __shared__ float2 lds[NFFT];
    __shared__ float2 sh[NFFT/2];      // summed half-spectrum (packed elem 0)
    const int tid = threadIdx.x;
    const int bid = blockIdx.x;        // j*BATCH + b
    const int b = bid & (BATCH - 1);
    const int j = bid >> 5;

    // Thread t accumulates complex positions 4*(t+256*c)+r, c<2, r<4.
    float2 a[8];
    #pragma unroll
    for (int k = 0; k < 8; ++k) a[k] = make_float2(0.f, 0.f);
    #pragma unroll
    for (int u = 0; u < 16; ++u) {
        const int4* row4 = (const int4*)(Ph + (size_t)((u*COUT + j)*BATCH + b) * (NFFT/2));
        #pragma unroll
        for (int c = 0; c < 2; ++c) {
            const int4 w = row4[tid + 256*c];
            const int ww[4] = { w.x, w.y, w.z, w.w };
            #pragma unroll
            for (int r = 0; r < 4; ++r) {
                __half2 h = *(const __half2*)&ww[r];
                float2 f = __half22float2(h);
                a[c*4+r] = cadd(a[c*4+r], f);
            }
        }
    }
    // sh[4*(tid+256c)+r] = a[4c+r]  -> float4 (b128) writes, conflict-free.
    float4* sh4 = (float4*)sh;
    #pragma unroll
    for (int c = 0; c < 2; ++c) {
        sh4[2*(tid + 256*c) + 0] = make_float4(a[c*4+0].x, a[c*4+0].y, a[c*4+1].x, a[c*4+1].y);
        sh4[2*(tid + 256*c) + 1] = make_float4(a[c*4+2].x, a[c*4+2].y, a[c*4+3].x, a[c*4+3].y);
    }
    __syncthreads();

    const float dc  = sh[0].x;         // broadcast reads
    const float nyq = sh[0].y;
    float2 v[16];
    #pragma unroll
    for (int k = 0; k < 8; ++k) v[k] = sh[tid + 256*k];
    if (tid == 0) v[0] = make_float2(dc, 0.0f);
    #pragma unroll
    for (int k = 8; k < 16; ++k) {
        const int m = 4096 - (tid + 256*k);          // mirror index in [1,2048]
        if (m == 2048) {                              // only tid==0, k==8
            v[k] = make_float2(nyq, 0.0f);
        } else {
            float2 c = sh[m];
            v[k] = make_float2(c.x, -c.y);            // conj
        }
    }
    // no barrier needed: fft writes lds[], sh[] untouched
    fft4096_r16<1>(v, lds, tid);
    const float invn = 1.0f / (float)NFFT;
    float* orow = out + (size_t)bid * NFFT;
    #pragma unroll
    for (int k = 0; k < 16; ++k) orow[tid + 256*k] = v[k].x * invn;
}

extern "C" void kernel_launch(void* const* d_in, const int* in_sizes, int n_in,
                              void* d_out, int out_size, void* d_ws, size_t ws_size,
                              hipStream_t stream) {
    const float* x = (const float*)d_in[0];   // (CIN, B, N)
    const float* G = (const float*)d_in[1];   // (CIN, COUT, R, N)
    const float* H = (const float*)d_in[2];   // (CIN, COUT, R, N)
    float* out = (float*)d_out;               // (COUT, B, N)

    float2*  Hf = (float2*)d_ws;                    // 64 rows  (2 MB)
    float2*  Gf = Hf + (size_t)64 * NFFT;           // 64 rows  (2 MB)
    float2*  Xf = Gf + (size_t)64 * NFFT;           // 128 rows (4 MB)
    __half2* Ph = (__half2*)(Xf + (size_t)128 * NFFT); // 2048 half-rows x 2048 h2 (16 MB)

    ldr_pre_k<<<256, NT, 0, stream>>>(x, G, H, Hf, Gf, Xf);
    ldr_mid_k<<<CIN * COUT * RANK * BATCH, NT, 0, stream>>>(Hf, Xf, Gf, Ph);
    ldr_fin_k<<<COUT * BATCH, NT, 0, stream>>>(Ph, out);
}

// Round 11
// 91.209 us; speedup vs baseline: 1.4847x; 1.1465x over previous
//
#include <hip/hip_runtime.h>
#include <hip/hip_fp16.h>
#include <math.h>

// LDR toep_corner via FFT chain, radix-16 registerized FFT (4096 = 16^3).
// out[j,b] = Re ifft( sum_{i,s} Gf_ijs . fft( D . fft( Hf_ijs . Xf_ib ) ) )
// Hf = fft(D.H), Xf = ifft(conj(D).x), Gf = fft(G), D_k = exp(i*pi*k/N).
//
// R11: two-for-one real pack in mid. t_s = D.fft(Hf_s.Xf) is REAL (it is
// C_{-1}(H_s)^T x, a real matrix times a real vector). For a rank pair
// (s0,s1): one FFT of P0+i*P1 -> W0+i*W1; D-mult -> t0+i*t1; one FFT -> Z;
// Hermitian unpack fft(t0)=(Z(k)+conj(Z(-k)))/2, fft(t1)=-i(Z(k)-conj(Z(-k)))/2;
// Y = g0.fft(t0)+g1.fft(t1). Mid FFTs 4096->2048, grid 1024, and NO registers
// live across FFT calls (R9's spill trap structurally avoided). Ph 16->8
// planes fp16 (8 MB). Mirror exchange stages only the upper half in the FFT
// LDS buffer; mirror reads are stride-1 descending (conflict-free).
// Fixed cost: ~44us of dur is the harness's 256MB d_ws 0xAA fill.

#define NFFT  4096
#define NT    256
#define CIN   4
#define COUT  4
#define RANK  4
#define BATCH 32
#define PI_F  3.14159265358979323846f

__device__ __forceinline__ float2 cmul(float2 a, float2 b) {
    return make_float2(a.x*b.x - a.y*b.y, a.x*b.y + a.y*b.x);
}
__device__ __forceinline__ float2 cadd(float2 a, float2 b){ return make_float2(a.x+b.x, a.y+b.y); }
__device__ __forceinline__ float2 csub(float2 a, float2 b){ return make_float2(a.x-b.x, a.y-b.y); }

// LDS bank swizzle (R2-proven: SQ_LDS_BANK_CONFLICT ~ 0).
__device__ __forceinline__ int SW(int e){ return e ^ ((e >> 4) & 15); }

// 16-point DFT in registers, natural order in/out (R2-proven numerics).
template<int SIGN>
__device__ __forceinline__ void dft16(float2 v[16]) {
    const float sgn = (float)SIGN;
    const float C8 = 0.923879532511287f, S8 = 0.382683432365090f, H2 = 0.707106781186548f;
    const float2 w1 = make_float2( C8,  sgn*S8);
    const float2 w2 = make_float2( H2,  sgn*H2);
    const float2 w3 = make_float2( S8,  sgn*C8);
    const float2 w4 = make_float2(0.f,  sgn);
    const float2 w6 = make_float2(-H2,  sgn*H2);
    const float2 w9 = make_float2(-C8, -sgn*S8);
    float2 t[16];
    #pragma unroll
    for (int p = 0; p < 4; ++p) {
        float2 a0 = v[p], a1 = v[p+4], a2 = v[p+8], a3 = v[p+12];
        float2 b0 = cadd(a0,a2), b1 = csub(a0,a2), b2 = cadd(a1,a3), b3 = csub(a1,a3);
        float2 ib3 = make_float2(-sgn*b3.y, sgn*b3.x);   // SIGN*i*b3
        float2 X0 = cadd(b0,b2), X2c = csub(b0,b2);
        float2 X1 = cadd(b1,ib3), X3 = csub(b1,ib3);
        if (p == 1) { X1 = cmul(X1,w1); X2c = cmul(X2c,w2); X3 = cmul(X3,w3); }
        else if (p == 2) { X1 = cmul(X1,w2); X2c = cmul(X2c,w4); X3 = cmul(X3,w6); }
        else if (p == 3) { X1 = cmul(X1,w3); X2c = cmul(X2c,w6); X3 = cmul(X3,w9); }
        t[4*p+0]=X0; t[4*p+1]=X1; t[4*p+2]=X2c; t[4*p+3]=X3;
    }
    #pragma unroll
    for (int q = 0; q < 4; ++q) {
        float2 a0 = t[q], a1 = t[q+4], a2 = t[q+8], a3 = t[q+12];
        float2 b0 = cadd(a0,a2), b1 = csub(a0,a2), b2 = cadd(a1,a3), b3 = csub(a1,a3);
        float2 ib3 = make_float2(-sgn*b3.y, sgn*b3.x);
        v[q+0]  = cadd(b0,b2);
        v[q+8]  = csub(b0,b2);
        v[q+4]  = cadd(b1,ib3);
        v[q+12] = csub(b1,ib3);
    }
}

// v[k] *= e^{i*k*ang}; two independent power chains (depth ~8 not 15).
__device__ __forceinline__ void twiddle16(float2 v[16], float ang) {
    float sn, cs; __sincosf(ang, &sn, &cs);
    float2 w  = make_float2(cs, sn);
    float2 w2 = cmul(w, w);
    float2 to = w;   // odd powers
    float2 te = w2;  // even powers
    v[1] = cmul(v[1], to);
    v[2] = cmul(v[2], te);
    #pragma unroll
    for (int k = 3; k < 16; k += 2) {
        to = cmul(to, w2); v[k] = cmul(v[k], to);
        if (k + 1 < 16) { te = cmul(te, w2); v[k+1] = cmul(v[k+1], te); }
    }
}

// Stockham radix-16, 3 stages, single 32KB buffer (R2-proven).
// Input: v[r] = x[tid + 256r]. Output: v[k] = X[tid + 256k].
// Trailing barrier: lds reusable by caller on exit.
template<int SIGN>
__device__ void fft4096_r16(float2 v[16], float2* lds, int tid) {
    dft16<SIGN>(v);
    twiddle16(v, (float)SIGN * 2.0f * PI_F * (float)tid / 4096.0f);
    #pragma unroll
    for (int k = 0; k < 16; ++k) lds[SW(16*tid + k)] = v[k];
    __syncthreads();
    #pragma unroll
    for (int r = 0; r < 16; ++r) v[r] = lds[SW(tid + 256*r)];
    dft16<SIGN>(v);
    twiddle16(v, (float)SIGN * 2.0f * PI_F * (float)(tid >> 4) / 256.0f);
    __syncthreads();                       // in-place: all reads before any write
    {
        const int q = tid & 15, p = tid >> 4;
        #pragma unroll
        for (int k = 0; k < 16; ++k) lds[SW(q + 256*p + 16*k)] = v[k];
    }
    __syncthreads();
    #pragma unroll
    for (int r = 0; r < 16; ++r) v[r] = lds[SW(tid + 256*r)];
    dft16<SIGN>(v);
    __syncthreads();                       // lds reusable by caller
}

// ---- Kernel A: precompute Hf (64 rows), Gf (64 rows), Xf (128 rows) ----
__global__ __launch_bounds__(NT, 2) void ldr_pre_k(
    const float* __restrict__ x, const float* __restrict__ G, const float* __restrict__ H,
    float2* __restrict__ Hf, float2* __restrict__ Gf, float2* __restrict__ Xf)
{
    __shared__ float2 lds[NFFT];
    const int tid = threadIdx.x;
    const int bid = blockIdx.x;
    float2 v[16];
    if (bid < 64) {
        const float* h = H + (size_t)bid * NFFT;
        float sn, cs; __sincosf(PI_F * (float)tid / (float)NFFT, &sn, &cs);
        float2 d = make_float2(cs, sn);
        const float2 dstep = make_float2(0.980785280403230449f, 0.195090322016128268f); // e^{i*pi/16}
        #pragma unroll
        for (int k = 0; k < 16; ++k) {
            float hv = h[tid + 256*k];
            v[k] = make_float2(d.x*hv, d.y*hv);
            d = cmul(d, dstep);
        }
        fft4096_r16<-1>(v, lds, tid);
        float2* o = Hf + (size_t)bid * NFFT;
        #pragma unroll
        for (int k = 0; k < 16; ++k) o[tid + 256*k] = v[k];
    } else if (bid < 128) {
        const int row = bid - 64;
        const float* g = G + (size_t)row * NFFT;
        #pragma unroll
        for (int k = 0; k < 16; ++k) v[k] = make_float2(g[tid + 256*k], 0.0f);
        fft4096_r16<-1>(v, lds, tid);
        float2* o = Gf + (size_t)row * NFFT;
        #pragma unroll
        for (int k = 0; k < 16; ++k) o[tid + 256*k] = v[k];
    } else {
        const int row = bid - 128;
        const float* xp = x + (size_t)row * NFFT;
        float sn, cs; __sincosf(PI_F * (float)tid / (float)NFFT, &sn, &cs);
        float2 d = make_float2(cs, -sn);                                                 // conj(D)
        const float2 dstep = make_float2(0.980785280403230449f, -0.195090322016128268f);
        #pragma unroll
        for (int k = 0; k < 16; ++k) {
            float xv = xp[tid + 256*k];
            v[k] = make_float2(d.x*xv, d.y*xv);
            d = cmul(d, dstep);
        }
        fft4096_r16<1>(v, lds, tid);
        const float invn = 1.0f / (float)NFFT;
        float2* o = Xf + (size_t)row * NFFT;
        #pragma unroll
        for (int k = 0; k < 16; ++k) o[tid + 256*k] = make_float2(v[k].x*invn, v[k].y*invn);
    }
}

// ---- Kernel B: middle. grid 1024 = (ij*2 + pr)(32) x b(32); one rank PAIR
// (s = 2pr, 2pr+1) per wg via the two-for-one real pack. Two full FFTs, no
// registers live across FFT calls. Store lower-half Y (Hermitian) as fp16,
// DC.x / Nyquist.x packed into element 0. Plane u = i*2+pr (8 planes),
// row ((u*COUT + j)*BATCH + b), 2048 half2.
__global__ __launch_bounds__(NT, 2) void ldr_mid_k(
    const float2* __restrict__ Hf, const float2* __restrict__ Xf,
    const float2* __restrict__ Gf, __half2* __restrict__ Ph)
{
    __shared__ float2 lds[NFFT];
    const int tid = threadIdx.x;
    const int bid = blockIdx.x;
    const int b   = bid & (BATCH - 1);
    const int ip  = bid >> 5;           // ij*2 + pr, [0,32)
    const int pr  = ip & 1;
    const int ij  = ip >> 1;
    const int i   = ij >> 2;            // COUT = 4
    const int j   = ij & 3;
    const int r0  = ij*RANK + 2*pr;     // rows s0 = r0, s1 = r0+1
    const float2* xrow = Xf + (size_t)(i*BATCH + b) * NFFT;
    const float2* h0 = Hf + (size_t)r0 * NFFT;
    const float2* h1 = h0 + NFFT;
    const float2* g0 = Gf + (size_t)r0 * NFFT;
    const float2* g1 = g0 + NFFT;

    // P = (h0.x) + i*(h1.x)  (complex combine of two complex products)
    float2 v[16];
    #pragma unroll
    for (int k = 0; k < 16; ++k) {
        const int e = tid + 256*k;
        const float2 xv = xrow[e];
        const float2 a  = cmul(h0[e], xv);
        const float2 c  = cmul(h1[e], xv);
        v[k] = make_float2(a.x - c.y, a.y + c.x);
    }
    fft4096_r16<-1>(v, lds, tid);
    // D-mult: z = D.(W0 + i W1) = t0 + i t1, t real. e = tid+256k.
    {
        float sn, cs; __sincosf(PI_F * (float)tid / (float)NFFT, &sn, &cs);
        float2 d = make_float2(cs, sn);
        const float2 dstep = make_float2(0.980785280403230449f, 0.195090322016128268f);
        #pragma unroll
        for (int k = 0; k < 16; ++k) { v[k] = cmul(v[k], d); d = cmul(d, dstep); }
    }
    fft4096_r16<-1>(v, lds, tid);       // Z = fft(t0) + i*fft(t1); lds free after

    // Stage upper half of Z for mirror access (mirror of any e in [1,2047]
    // lies in [2049,4095]; e=0 and e=2048 are self-mirrors held in regs).
    #pragma unroll
    for (int k = 8; k < 16; ++k) lds[SW(tid + 256*k)] = v[k];
    __syncthreads();

    const int u = i*2 + pr;             // plane in [0,8)
    __half2* prow = Ph + (size_t)((u*COUT + j)*BATCH + b) * (NFFT/2);
    #pragma unroll
    for (int k = 0; k < 8; ++k) {
        const int e = tid + 256*k;
        const float2 Zk = v[k];
        float2 Zm;
        if (e == 0) Zm = Zk;                 // tid==0, k==0 only
        else        Zm = lds[SW(4096 - e)];
        // V1 = fft(t0)(e) = (Zk + conj(Zm))/2 ; V2 = fft(t1)(e) = -i(Zk - conj(Zm))/2
        const float2 V1 = make_float2(0.5f*(Zk.x + Zm.x), 0.5f*(Zk.y - Zm.y));
        const float2 V2 = make_float2(0.5f*(Zk.y + Zm.y), 0.5f*(Zm.x - Zk.x));
        float2 Y = cadd(cmul(g0[e], V1), cmul(g1[e], V2));
        if (k == 0 && tid == 0) {
            // Nyquist e=2048 is self-mirror, Z(2048) = v[8] of thread 0:
            // fft(t0)(2048) = Re Z, fft(t1)(2048) = Im Z; g at Nyquist real.
            const float2 Zn = v[8];
            const float Ynyq = g0[2048].x * Zn.x + g1[2048].x * Zn.y;
            Y = make_float2(Y.x, Ynyq);      // pack DC.x / Nyq.x
        }
        prow[e] = __floats2half2_rn(Y.x, Y.y);
    }
}

// ---- Kernel C: final. grid 128 = (j,b). Sum 8 fp16 half-rows via int4
// loads, mirror upper half by conjugate symmetry, one inverse FFT, write Re/N.
__global__ __launch_bounds__(NT, 2) void ldr_fin_k(
    const __half2* __restrict__ Ph, float* __restrict__ out)
{
    __shared__ float2 lds[NFFT];
    __shared__ float2 sh[NFFT/2];      // summed half-spectrum (packed elem 0)
    const int tid = threadIdx.x;
    const int bid = blockIdx.x;        // j*BATCH + b
    const int b = bid & (BATCH - 1);
    const int j = bid >> 5;

    // Thread t accumulates complex positions 4*(t+256*c)+r, c<2, r<4.
    float2 a[8];
    #pragma unroll
    for (int k = 0; k < 8; ++k) a[k] = make_float2(0.f, 0.f);
    #pragma unroll
    for (int u = 0; u < 8; ++u) {
        const int4* row4 = (const int4*)(Ph + (size_t)((u*COUT + j)*BATCH + b) * (NFFT/2));
        #pragma unroll
        for (int c = 0; c < 2; ++c) {
            const int4 w = row4[tid + 256*c];
            const int ww[4] = { w.x, w.y, w.z, w.w };
            #pragma unroll
            for (int r = 0; r < 4; ++r) {
                __half2 h = *(const __half2*)&ww[r];
                float2 f = __half22float2(h);
                a[c*4+r] = cadd(a[c*4+r], f);
            }
        }
    }
    // sh[4*(tid+256c)+r] = a[4c+r]  -> float4 (b128) writes, conflict-free.
    float4* sh4 = (float4*)sh;
    #pragma unroll
    for (int c = 0; c < 2; ++c) {
        sh4[2*(tid + 256*c) + 0] = make_float4(a[c*4+0].x, a[c*4+0].y, a[c*4+1].x, a[c*4+1].y);
        sh4[2*(tid + 256*c) + 1] = make_float4(a[c*4+2].x, a[c*4+2].y, a[c*4+3].x, a[c*4+3].y);
    }
    __syncthreads();

    const float dc  = sh[0].x;         // broadcast reads
    const float nyq = sh[0].y;
    float2 v[16];
    #pragma unroll
    for (int k = 0; k < 8; ++k) v[k] = sh[tid + 256*k];
    if (tid == 0) v[0] = make_float2(dc, 0.0f);
    #pragma unroll
    for (int k = 8; k < 16; ++k) {
        const int m = 4096 - (tid + 256*k);          // mirror index in [1,2048]
        if (m == 2048) {                              // only tid==0, k==8
            v[k] = make_float2(nyq, 0.0f);
        } else {
            float2 c = sh[m];
            v[k] = make_float2(c.x, -c.y);            // conj
        }
    }
    // no barrier needed: fft writes lds[], sh[] untouched
    fft4096_r16<1>(v, lds, tid);
    const float invn = 1.0f / (float)NFFT;
    float* orow = out + (size_t)bid * NFFT;
    #pragma unroll
    for (int k = 0; k < 16; ++k) orow[tid + 256*k] = v[k].x * invn;
}

extern "C" void kernel_launch(void* const* d_in, const int* in_sizes, int n_in,
                              void* d_out, int out_size, void* d_ws, size_t ws_size,
                              hipStream_t stream) {
    const float* x = (const float*)d_in[0];   // (CIN, B, N)
    const float* G = (const float*)d_in[1];   // (CIN, COUT, R, N)
    const float* H = (const float*)d_in[2];   // (CIN, COUT, R, N)
    float* out = (float*)d_out;               // (COUT, B, N)

    float2*  Hf = (float2*)d_ws;                    // 64 rows  (2 MB)
    float2*  Gf = Hf + (size_t)64 * NFFT;           // 64 rows  (2 MB)
    float2*  Xf = Gf + (size_t)64 * NFFT;           // 128 rows (4 MB)
    __half2* Ph = (__half2*)(Xf + (size_t)128 * NFFT); // 1024 half-rows x 2048 h2 (8 MB)

    ldr_pre_k<<<256, NT, 0, stream>>>(x, G, H, Hf, Gf, Xf);
    ldr_mid_k<<<CIN * COUT * RANK * BATCH / 2, NT, 0, stream>>>(Hf, Xf, Gf, Ph);
    ldr_fin_k<<<COUT * BATCH, NT, 0, stream>>>(Ph, out);
}